// Round 4
// baseline (489.635 us; speedup 1.0000x reference)
//
#include <hip/hip_runtime.h>
#include <math.h>

#define DD    256
#define PLQ   65536           // plane elems (u16) = 256*256
#define SLOTB 131072          // complex slot elems (u16): re plane + im plane
#define NTS   128
#define DT_C  0.02f

typedef unsigned short u16;
typedef unsigned int   u32;
typedef __attribute__((ext_vector_type(8))) short s16x8;
typedef __attribute__((ext_vector_type(4))) float f32x4;

typedef __attribute__((address_space(1))) const unsigned int GU32;
typedef __attribute__((address_space(3))) unsigned int LU32;

__device__ __forceinline__ u32 swz(u32 off) {       // 16B-chunk XOR swizzle (involution)
    return off ^ (((off >> 7) & 3u) << 4);
}
__device__ __forceinline__ u16 f2bf(float f) {
    u32 u = __float_as_uint(f);
    return (u16)((u + 0x7FFFu + ((u >> 16) & 1u)) >> 16);
}
__device__ __forceinline__ float bf2f(u16 h) {
    return __uint_as_float(((u32)h) << 16);
}
__device__ __forceinline__ void gll16(const u16* g, char* ldsBase, u32 ldsByteOff) {
    u32 off = (u32)__builtin_amdgcn_readfirstlane((int)ldsByteOff);
    __builtin_amdgcn_global_load_lds((GU32*)g, (LU32*)(ldsBase + off), 16, 0, 0);
}

// ---------------------------------------------------------------------------
// build: X = DT * A_ts  (bf16), written in BOTH N (row-major) and T
// (col-major) layouts via LDS tiled transpose. Block = 64x64 tile of one ts.
// ---------------------------------------------------------------------------
__global__ __launch_bounds__(256)
void build_kernel(const float* __restrict__ cr, const float* __restrict__ ci,
                  const float* __restrict__ dre, const float* __restrict__ dimg,
                  const float* __restrict__ gre, const float* __restrict__ gim,
                  u16* __restrict__ Xn, u16* __restrict__ Xt, int ts0)
{
    __shared__ u16 tre[64][66], tim[64][66];

    const int ts = blockIdx.y;
    const int k  = ts0 + ts;
    const int bx = blockIdx.x;                 // 0..15
    const int r0 = (bx >> 2) * 64, c0 = (bx & 3) * 64;
    const int t  = threadIdx.x;
    const int tr = t >> 4;                     // 0..15
    const int tc = (t & 15) * 4;               // 0..60

    const float c0f = cr[2*k], c1f = cr[2*k+1];
    const float e0f = ci[2*k], e1f = ci[2*k+1];

    u16* XN = Xn + (size_t)ts * SLOTB;
    u16* XT = Xt + (size_t)ts * SLOTB;

    #pragma unroll
    for (int g = 0; g < 4; ++g) {
        const int lr  = g*16 + tr;
        const int idx = (r0 + lr)*DD + (c0 + tc);
        const float4 g0r = *(const float4*)&gre[0*PLQ + idx];
        const float4 g1r = *(const float4*)&gre[1*PLQ + idx];
        const float4 g2r = *(const float4*)&gre[2*PLQ + idx];
        const float4 g3r = *(const float4*)&gre[3*PLQ + idx];
        const float4 g0i = *(const float4*)&gim[0*PLQ + idx];
        const float4 g1i = *(const float4*)&gim[1*PLQ + idx];
        const float4 g2i = *(const float4*)&gim[2*PLQ + idx];
        const float4 g3i = *(const float4*)&gim[3*PLQ + idx];
        const float4 d_r = *(const float4*)&dre[idx];
        const float4 d_i = *(const float4*)&dimg[idx];
        const float* gr00 = &g0r.x; const float* gr01 = &g1r.x;
        const float* gr10 = &g2r.x; const float* gr11 = &g3r.x;
        const float* gi00 = &g0i.x; const float* gi01 = &g1i.x;
        const float* gi10 = &g2i.x; const float* gi11 = &g3i.x;
        const float* dr4  = &d_r.x; const float* di4  = &d_i.x;
        ushort4 hr, hi;
        u16* hrp = &hr.x; u16* hip = &hi.x;
        #pragma unroll
        for (int j = 0; j < 4; ++j) {
            const float are = dr4[j] + c0f*(gr00[j]+gr01[j]) + c1f*(gr10[j]+gr11[j])
                                     - e0f*(gi00[j]-gi01[j]) - e1f*(gi10[j]-gi11[j]);
            const float aim = di4[j] + c0f*(gi00[j]+gi01[j]) + c1f*(gi10[j]+gi11[j])
                                     + e0f*(gr00[j]-gr01[j]) + e1f*(gr10[j]-gr11[j]);
            hrp[j] = f2bf(DT_C * are);
            hip[j] = f2bf(DT_C * aim);
            tre[lr][tc + j] = hrp[j];
            tim[lr][tc + j] = hip[j];
        }
        *(ushort4*)&XN[idx]       = hr;
        *(ushort4*)&XN[PLQ + idx] = hi;
    }
    __syncthreads();
    #pragma unroll
    for (int g = 0; g < 4; ++g) {
        const int trow = g*16 + tr;            // local col of X
        const int oidx = (c0 + trow)*DD + r0 + tc;
        ushort4 hr, hi;
        hr.x = tre[tc+0][trow]; hr.y = tre[tc+1][trow];
        hr.z = tre[tc+2][trow]; hr.w = tre[tc+3][trow];
        hi.x = tim[tc+0][trow]; hi.y = tim[tc+1][trow];
        hi.z = tim[tc+2][trow]; hi.w = tim[tc+3][trow];
        *(ushort4*)&XT[oidx]       = hr;
        *(ushort4*)&XT[PLQ + oidx] = hi;
    }
}

// ---------------------------------------------------------------------------
// Batched complex bf16 MFMA GEMM, 128x128 tile, 4 waves, BK=32 (m97-style):
//   acc = A@B  (A: N-layout global; Bt: T-layout global; both via gll16 w16)
//   N-write: aN*acc + bN1*X1 + bN2*X2  (row-major)
//   T-write: aT*acc + bT1*X1 + bT2*X2  (col-major)
// Per wave: 64x64 output (4x4 16x16 frags). 256 MFMA / block / K-tile.
// ---------------------------------------------------------------------------
__global__ __launch_bounds__(256, 2)
void cgemm(const u16* __restrict__ Ab, const u16* __restrict__ Btb,
           u16* __restrict__ outN, u16* __restrict__ outT,
           const u16* __restrict__ X1b, const u16* __restrict__ X2b,
           float aN, float bN1, float bN2,
           float aT, float bT1, float bT2,
           int aS, int aO, int bS, int bO, int cS, int cO,
           int x1S, int x1O, int x2S, int x2O)
{
    __shared__ char lds[32768];   // Are[128][32] | Aim | Bre[128][32](n-major) | Bim

    // ---- bijective XCD-chunked block swizzle (nwg%8==0 when nz%2==0) ----
    const u32 nwg = 4u * (u32)gridDim.z;
    const u32 wg  = (u32)blockIdx.x + 2u*(u32)blockIdx.y + 4u*(u32)blockIdx.z;
    u32 w = wg;
    if ((nwg & 7u) == 0u) { const u32 q = nwg >> 3; w = (wg & 7u) * q + (wg >> 3); }
    const int bn = (int)(w & 1u) * 128;
    const int bm = (int)((w >> 1) & 1u) * 128;
    const int z  = (int)(w >> 2);

    const u16* __restrict__ A  = Ab  + (size_t)(z*aS + aO) * SLOTB;
    const u16* __restrict__ Bt = Btb + (size_t)(z*bS + bO) * SLOTB;

    const int t = threadIdx.x;

    // staging: dest chunk D=t*16 (half0) / +4096 (half1); logical L=swz(D)
    const u32 D0 = (u32)t * 16u;
    const u32 L0 = swz(D0);
    const int sr = (int)(L0 >> 6);             // tile row 0..63 (half1: +64)
    const int sk = (int)((L0 & 63u) >> 1);     // k elem offset (16B aligned)
    const u32 wvoff = ((u32)(t >> 6)) * 1024u;

    const u16* pAr0 = A  + (size_t)(bm + sr     )*DD + sk;
    const u16* pAr1 = A  + (size_t)(bm + sr + 64)*DD + sk;
    const u16* pBr0 = Bt + (size_t)(bn + sr     )*DD + sk;
    const u16* pBr1 = Bt + (size_t)(bn + sr + 64)*DD + sk;

    const int wv = t >> 6, ln = t & 63;
    const int wrow = (wv >> 1) * 64, wcol = (wv & 1) * 64;
    const int lg = ln >> 4, lc = ln & 15;

    f32x4 accR[4][4], accI[4][4];
    #pragma unroll
    for (int i = 0; i < 4; ++i)
        #pragma unroll
        for (int j = 0; j < 4; ++j) {
            accR[i][j] = (f32x4){0.f,0.f,0.f,0.f};
            accI[i][j] = (f32x4){0.f,0.f,0.f,0.f};
        }

    for (int k0 = 0; k0 < DD; k0 += 32) {
        __syncthreads();
        gll16(pAr0 + k0,       lds,     0u + wvoff);
        gll16(pAr1 + k0,       lds,  4096u + wvoff);
        gll16(pAr0 + PLQ + k0, lds,  8192u + wvoff);
        gll16(pAr1 + PLQ + k0, lds, 12288u + wvoff);
        gll16(pBr0 + k0,       lds, 16384u + wvoff);
        gll16(pBr1 + k0,       lds, 20480u + wvoff);
        gll16(pBr0 + PLQ + k0, lds, 24576u + wvoff);
        gll16(pBr1 + PLQ + k0, lds, 28672u + wvoff);
        __syncthreads();

        s16x8 ar[4], ai[4], br[4], bi[4];
        #pragma unroll
        for (int fm = 0; fm < 4; ++fm) {
            const u32 so = swz((u32)(wrow + fm*16 + lc)*64u + (u32)lg*16u);
            ar[fm] = *(const s16x8*)(lds + so);
            ai[fm] = *(const s16x8*)(lds + 8192 + so);
        }
        #pragma unroll
        for (int fn = 0; fn < 4; ++fn) {
            const u32 so = swz((u32)(wcol + fn*16 + lc)*64u + (u32)lg*16u);
            br[fn] = *(const s16x8*)(lds + 16384 + so);
            bi[fn] = *(const s16x8*)(lds + 24576 + so);
        }
        // pass 1: imag acc (uses ai positively)
        #pragma unroll
        for (int fm = 0; fm < 4; ++fm)
            #pragma unroll
            for (int fn = 0; fn < 4; ++fn) {
                accI[fm][fn] = __builtin_amdgcn_mfma_f32_16x16x32_bf16(ar[fm], bi[fn], accI[fm][fn], 0, 0, 0);
                accI[fm][fn] = __builtin_amdgcn_mfma_f32_16x16x32_bf16(ai[fm], br[fn], accI[fm][fn], 0, 0, 0);
            }
        // flip sign of ai in place, then real acc: ar@br + (-ai)@bi
        #pragma unroll
        for (int fm = 0; fm < 4; ++fm) ai[fm] ^= (short)0x8000u;
        #pragma unroll
        for (int fm = 0; fm < 4; ++fm)
            #pragma unroll
            for (int fn = 0; fn < 4; ++fn) {
                accR[fm][fn] = __builtin_amdgcn_mfma_f32_16x16x32_bf16(ar[fm], br[fn], accR[fm][fn], 0, 0, 0);
                accR[fm][fn] = __builtin_amdgcn_mfma_f32_16x16x32_bf16(ai[fm], bi[fn], accR[fm][fn], 0, 0, 0);
            }
    }

    // ---- epilogue ----
    u16* oN = outN ? outN + (size_t)(z*cS + cO) * SLOTB : nullptr;
    u16* oT = outT ? outT + (size_t)(z*cS + cO) * SLOTB : nullptr;
    const u16* x1 = X1b ? X1b + (size_t)(z*x1S + x1O) * SLOTB : nullptr;
    const u16* x2 = X2b ? X2b + (size_t)(z*x2S + x2O) * SLOTB : nullptr;

    #pragma unroll
    for (int fm = 0; fm < 4; ++fm)
        #pragma unroll
        for (int fn = 0; fn < 4; ++fn) {
            const int rb = bm + wrow + fm*16 + lg*4;
            const int c  = bn + wcol + fn*16 + lc;
            u16 tR[4], tI[4];
            #pragma unroll
            for (int j = 0; j < 4; ++j) {
                const int r = rb + j;
                float x1r = 0.f, x1i = 0.f, x2r = 0.f, x2i = 0.f;
                if (x1) { x1r = bf2f(x1[(size_t)r*DD + c]);
                          x1i = bf2f(x1[PLQ + (size_t)r*DD + c]); }
                if (x2) { x2r = bf2f(x2[(size_t)r*DD + c]);
                          x2i = bf2f(x2[PLQ + (size_t)r*DD + c]); }
                if (oN) {
                    oN[(size_t)r*DD + c]       = f2bf(aN*accR[fm][fn][j] + bN1*x1r + bN2*x2r);
                    oN[PLQ + (size_t)r*DD + c] = f2bf(aN*accI[fm][fn][j] + bN1*x1i + bN2*x2i);
                }
                tR[j] = f2bf(aT*accR[fm][fn][j] + bT1*x1r + bT2*x2r);
                tI[j] = f2bf(aT*accI[fm][fn][j] + bT1*x1i + bT2*x2i);
            }
            if (oT) {
                *(ushort4*)(oT + (size_t)c*DD + rb)       = make_ushort4(tR[0], tR[1], tR[2], tR[3]);
                *(ushort4*)(oT + PLQ + (size_t)c*DD + rb) = make_ushort4(tI[0], tI[1], tI[2], tI[3]);
            }
        }
}

// ---------------------------------------------------------------------------
// final: v = s0 + Etot@s0 ; c = sum(v[diag]) ; sT = v/c ; fid = ||sT-tgt||_F
// ---------------------------------------------------------------------------
__global__ __launch_bounds__(256)
void final_kernel(const u16* __restrict__ Et,
                  const float* __restrict__ s0r, const float* __restrict__ s0i,
                  const float* __restrict__ tgr, const float* __restrict__ tgi,
                  float* __restrict__ out, int outSize)
{
    __shared__ float sr[DD], si[DD], vr[DD], vi[DD], red[DD];
    __shared__ float cR, cI;
    const int t = threadIdx.x;
    sr[t] = s0r[t];
    si[t] = s0i[t];
    __syncthreads();

    const u16* Er = Et + (size_t)t*DD;
    const u16* Ei = Et + PLQ + (size_t)t*DD;
    float ar = sr[t], ai = si[t];
    for (int kk = 0; kk < DD/8; ++kk) {
        const s16x8 er = *(const s16x8*)(Er + kk*8);
        const s16x8 ei = *(const s16x8*)(Ei + kk*8);
        #pragma unroll
        for (int j = 0; j < 8; ++j) {
            const float pr = bf2f((u16)er[j]);
            const float pi = bf2f((u16)ei[j]);
            const int k = kk*8 + j;
            ar += pr*sr[k] - pi*si[k];
            ai += pr*si[k] + pi*sr[k];
        }
    }
    vr[t] = ar; vi[t] = ai;
    __syncthreads();

    if (t == 0) {
        float xr = 0.f, xi = 0.f;
        for (int i = 0; i < 16; ++i) { xr += vr[i*17]; xi += vi[i*17]; }
        cR = xr; cI = xi;
    }
    __syncthreads();

    const float den = cR*cR + cI*cI;
    const float str = (ar*cR + ai*cI) / den;
    const float sti = (ai*cR - ar*cI) / den;

    const float dr = str - tgr[t];
    const float di = sti - tgi[t];
    red[t] = dr*dr + di*di;
    __syncthreads();
    for (int s = 128; s > 0; s >>= 1) {
        if (t < s) red[t] += red[t + s];
        __syncthreads();
    }
    const float fid = sqrtf(red[0]);

    if (outSize >= 2*DD + 1) {
        out[2*t] = str; out[2*t+1] = sti;
        if (t == 0) out[2*DD] = fid;
    } else if (outSize == 2*DD) {
        out[2*t] = str; out[2*t+1] = sti;
    } else {
        out[t] = str;
        if (t == 0 && outSize > DD) out[DD] = fid;
    }
}

// ---------------------------------------------------------------------------
extern "C" void kernel_launch(void* const* d_in, const int* in_sizes, int n_in,
                              void* d_out, int out_size, void* d_ws, size_t ws_size,
                              hipStream_t stream)
{
    (void)in_sizes; (void)n_in;
    const float* cr   = (const float*)d_in[0];
    const float* ci   = (const float*)d_in[1];
    const float* dre  = (const float*)d_in[2];
    const float* dimg = (const float*)d_in[3];
    const float* gre  = (const float*)d_in[4];
    const float* gim  = (const float*)d_in[5];
    const float* s0r  = (const float*)d_in[6];
    const float* s0i  = (const float*)d_in[7];
    const float* tgr  = (const float*)d_in[8];
    const float* tgi  = (const float*)d_in[9];

    // Taylor-6 coefficients 1/k!  (||X*DT|| ~ 0.3 -> truncation < 4e-8)
    const float c1 = 1.f, c2 = 0.5f, c3 = 1.f/6.f,
                c4 = 1.f/24.f, c5 = 1.f/120.f, c6 = 1.f/720.f;

    u16* ws = (u16*)d_ws;
    u16* P  = ws;                          // 128 N-slots: expm deviations E_ts
    u16* PT = ws + 128L * SLOTB;           // 128 T-slots
    u16* CB = ws + 256L * SLOTB;           // chunk region: 5C slots

    long availU = (long)(ws_size / 2) - 256L * SLOTB;
    int C = availU > 0 ? (int)(availU / (5L * SLOTB)) : 8;
    if (C > NTS) C = NTS;
    if (C < 8)   C = 8;

    for (int ts0 = 0; ts0 < NTS; ts0 += C) {
        int nb = NTS - ts0; if (nb > C) nb = C;
        u16* Xn  = CB;
        u16* Xt  = CB + 1L*C*SLOTB;
        u16* P2  = CB + 2L*C*SLOTB;
        u16* L3T = CB + 3L*C*SLOTB;
        u16* MTt = CB + 4L*C*SLOTB;

        build_kernel<<<dim3(16, nb), 256, 0, stream>>>(
            cr, ci, dre, dimg, gre, gim, Xn, Xt, ts0);

        const dim3 grid(2, 2, nb);
        // G1: P2 = X@X (N) ; L3T = c6*P2 + c5*X (T)
        cgemm<<<grid, 256, 0, stream>>>(Xn, Xt, P2, L3T, Xn, nullptr,
            1.f, 0.f, 0.f,  c6, c5, 0.f,
            1,0, 1,0, 1,0, 1,0, 0,0);
        // G2: MT = (P2@L3 + c3*X + c4*P2)^T
        cgemm<<<grid, 256, 0, stream>>>(P2, L3T, nullptr, MTt, Xn, P2,
            0.f, 0.f, 0.f,  1.f, c3, c4,
            1,0, 1,0, 1,0, 1,0, 1,0);
        // G3: E = P2@MT + c1*X + c2*P2  -> P[ts] (N) and PT[ts] (T)
        cgemm<<<grid, 256, 0, stream>>>(P2, MTt, P, PT, Xn, P2,
            1.f, c1, c2,  1.f, c1, c2,
            1,0, 1,0, 1,ts0, 1,0, 1,0);
    }

    // ---- product tree, in place: E' = Ea@Eb + Ea + Eb  (Ea = later half) ----
    int n = NTS, st = 1;
    while (n > 1) {
        const bool last = (n == 2);
        cgemm<<<dim3(2, 2, n/2), 256, 0, stream>>>(
            P, PT, P, last ? nullptr : PT, P, P,
            1.f, 1.f, 1.f,  1.f, 1.f, 1.f,
            2*st, st,   2*st, 0,   2*st, 0,   2*st, st,   2*st, 0);
        n >>= 1; st <<= 1;
    }

    final_kernel<<<1, 256, 0, stream>>>(P, s0r, s0i, tgr, tgi,
                                        (float*)d_out, out_size);
}

// Round 5
// 265.536 us; speedup vs baseline: 1.8439x; 1.8439x over previous
//
#include <hip/hip_runtime.h>
#include <math.h>

#define DD    256
#define PLQ   65536           // plane elems (u16) = 256*256
#define SLOTB 131072          // complex slot elems (u16): re plane + im plane
#define NTS   128
#define DT_C  0.02f

typedef unsigned short u16;
typedef unsigned int   u32;
typedef __attribute__((ext_vector_type(8))) short s16x8;
typedef __attribute__((ext_vector_type(4))) float f32x4;

typedef __attribute__((address_space(1))) const unsigned int GU32;
typedef __attribute__((address_space(3))) unsigned int LU32;

__device__ __forceinline__ u32 swz(u32 off) {       // 16B-chunk XOR swizzle (involution)
    return off ^ (((off >> 7) & 3u) << 4);
}
__device__ __forceinline__ u16 f2bf(float f) {
    u32 u = __float_as_uint(f);
    return (u16)((u + 0x7FFFu + ((u >> 16) & 1u)) >> 16);
}
__device__ __forceinline__ float bf2f(u16 h) {
    return __uint_as_float(((u32)h) << 16);
}
__device__ __forceinline__ void gll16(const u16* g, char* ldsBase, u32 ldsByteOff) {
    u32 off = (u32)__builtin_amdgcn_readfirstlane((int)ldsByteOff);
    __builtin_amdgcn_global_load_lds((GU32*)g, (LU32*)(ldsBase + off), 16, 0, 0);
}

// ---------------------------------------------------------------------------
// build: X = DT * A_ts (bf16), written in BOTH N and T layouts (LDS transpose).
// ---------------------------------------------------------------------------
__global__ __launch_bounds__(256)
void build_kernel(const float* __restrict__ cr, const float* __restrict__ ci,
                  const float* __restrict__ dre, const float* __restrict__ dimg,
                  const float* __restrict__ gre, const float* __restrict__ gim,
                  u16* __restrict__ Xn, u16* __restrict__ Xt, int ts0)
{
    __shared__ u16 tre[64][66], tim[64][66];

    const int ts = blockIdx.y;
    const int k  = ts0 + ts;
    const int bx = blockIdx.x;                 // 0..15
    const int r0 = (bx >> 2) * 64, c0 = (bx & 3) * 64;
    const int t  = threadIdx.x;
    const int tr = t >> 4;                     // 0..15
    const int tc = (t & 15) * 4;               // 0..60

    const float c0f = cr[2*k], c1f = cr[2*k+1];
    const float e0f = ci[2*k], e1f = ci[2*k+1];

    u16* XN = Xn + (size_t)ts * SLOTB;
    u16* XT = Xt + (size_t)ts * SLOTB;

    #pragma unroll
    for (int g = 0; g < 4; ++g) {
        const int lr  = g*16 + tr;
        const int idx = (r0 + lr)*DD + (c0 + tc);
        const float4 g0r = *(const float4*)&gre[0*PLQ + idx];
        const float4 g1r = *(const float4*)&gre[1*PLQ + idx];
        const float4 g2r = *(const float4*)&gre[2*PLQ + idx];
        const float4 g3r = *(const float4*)&gre[3*PLQ + idx];
        const float4 g0i = *(const float4*)&gim[0*PLQ + idx];
        const float4 g1i = *(const float4*)&gim[1*PLQ + idx];
        const float4 g2i = *(const float4*)&gim[2*PLQ + idx];
        const float4 g3i = *(const float4*)&gim[3*PLQ + idx];
        const float4 d_r = *(const float4*)&dre[idx];
        const float4 d_i = *(const float4*)&dimg[idx];
        const float* gr00 = &g0r.x; const float* gr01 = &g1r.x;
        const float* gr10 = &g2r.x; const float* gr11 = &g3r.x;
        const float* gi00 = &g0i.x; const float* gi01 = &g1i.x;
        const float* gi10 = &g2i.x; const float* gi11 = &g3i.x;
        const float* dr4  = &d_r.x; const float* di4  = &d_i.x;
        ushort4 hr, hi;
        u16* hrp = &hr.x; u16* hip = &hi.x;
        #pragma unroll
        for (int j = 0; j < 4; ++j) {
            const float are = dr4[j] + c0f*(gr00[j]+gr01[j]) + c1f*(gr10[j]+gr11[j])
                                     - e0f*(gi00[j]-gi01[j]) - e1f*(gi10[j]-gi11[j]);
            const float aim = di4[j] + c0f*(gi00[j]+gi01[j]) + c1f*(gi10[j]+gi11[j])
                                     + e0f*(gr00[j]-gr01[j]) + e1f*(gr10[j]-gr11[j]);
            hrp[j] = f2bf(DT_C * are);
            hip[j] = f2bf(DT_C * aim);
            tre[lr][tc + j] = hrp[j];
            tim[lr][tc + j] = hip[j];
        }
        *(ushort4*)&XN[idx]       = hr;
        *(ushort4*)&XN[PLQ + idx] = hi;
    }
    __syncthreads();
    #pragma unroll
    for (int g = 0; g < 4; ++g) {
        const int trow = g*16 + tr;            // local col of X
        const int oidx = (c0 + trow)*DD + r0 + tc;
        ushort4 hr, hi;
        hr.x = tre[tc+0][trow]; hr.y = tre[tc+1][trow];
        hr.z = tre[tc+2][trow]; hr.w = tre[tc+3][trow];
        hi.x = tim[tc+0][trow]; hi.y = tim[tc+1][trow];
        hi.z = tim[tc+2][trow]; hi.w = tim[tc+3][trow];
        *(ushort4*)&XT[oidx]       = hr;
        *(ushort4*)&XT[PLQ + oidx] = hi;
    }
}

// ---------------------------------------------------------------------------
// Batched complex bf16 MFMA GEMM, 64x64 tile, 4 waves, BK=32, DOUBLE-BUFFERED
// 2-phase pipeline (stage t+1 || compute t, one barrier per K-step).
//   acc = A@B. A: N-layout via gll16. B: TRB=0 -> T-layout via gll16;
//   TRB=1 -> N-layout, reg-load early + LDS scatter after MFMAs (T14 split).
//   N-write: aN*acc + bN1*X1 + bN2*X2 ; T-write: aT*acc + bT1*X1 + bT2*X2.
// ---------------------------------------------------------------------------
template<int TRB>
__global__ __launch_bounds__(256)
void cgemm(const u16* __restrict__ Ab, const u16* __restrict__ Bb,
           u16* __restrict__ outN, u16* __restrict__ outT,
           const u16* __restrict__ X1b, const u16* __restrict__ X2b,
           float aN, float bN1, float bN2,
           float aT, float bT1, float bT2,
           int aS, int aO, int bS, int bO, int cS, int cO,
           int x1S, int x1O, int x2S, int x2O)
{
    __shared__ char lds[32768];   // 2 x { Are[64][32] | Aim | Bre[64][32](n-major) | Bim }

    // ---- bijective XCD-chunked block swizzle (nwg = 16*nz, always %8==0) ----
    const u32 nwg = 16u * (u32)gridDim.z;
    const u32 wg  = (u32)blockIdx.x + 4u*(u32)blockIdx.y + 16u*(u32)blockIdx.z;
    const u32 q   = nwg >> 3;
    const u32 w   = (wg & 7u) * q + (wg >> 3);
    const int bn = (int)(w & 3u) * 64;
    const int bm = (int)((w >> 2) & 3u) * 64;
    const int z  = (int)(w >> 4);

    const u16* __restrict__ A = Ab + (size_t)(z*aS + aO) * SLOTB;
    const u16* __restrict__ B = Bb + (size_t)(z*bS + bO) * SLOTB;

    const int t = threadIdx.x;

    // gll16 staging mapping: dest chunk D=t*16 -> logical L=swz(D)
    const u32 D0 = (u32)t * 16u;
    const u32 L0 = swz(D0);
    const int sr = (int)(L0 >> 6);             // tile row 0..63
    const int sk = (int)((L0 & 63u) >> 1);     // k elem offset (16B aligned)
    const u32 wvoff = ((u32)(t >> 6)) * 1024u;

    const u16* pA = A + (size_t)(bm + sr)*DD + sk;
    const u16* pB = (TRB == 0) ? (B + (size_t)(bn + sr)*DD + sk) : nullptr;

    // TRB=1 staging mapping (B from N-layout [k][n])
    const int kRow = t >> 3;                   // 0..31
    const int nCh  = t & 7;                    // 0..7 -> n0 = nCh*8

    const int wv = t >> 6, ln = t & 63;
    const int wrow = (wv >> 1) * 32, wcol = (wv & 1) * 32;
    const int lg = ln >> 4, lc = ln & 15;

    f32x4 accR[2][2], accI[2][2];
    #pragma unroll
    for (int i = 0; i < 2; ++i)
        #pragma unroll
        for (int j = 0; j < 2; ++j) {
            accR[i][j] = (f32x4){0.f,0.f,0.f,0.f};
            accI[i][j] = (f32x4){0.f,0.f,0.f,0.f};
        }

    // ---- prologue: stage K-tile 0 into buffer 0 ----
    {
        gll16(pA,       lds,     0u + wvoff);
        gll16(pA + PLQ, lds,  4096u + wvoff);
        if (TRB == 0) {
            gll16(pB,       lds,  8192u + wvoff);
            gll16(pB + PLQ, lds, 12288u + wvoff);
        } else {
            const s16x8 vr = *(const s16x8*)(B +       (size_t)kRow*DD + bn + nCh*8);
            const s16x8 vi = *(const s16x8*)(B + PLQ + (size_t)kRow*DD + bn + nCh*8);
            #pragma unroll
            for (int e = 0; e < 8; ++e) {
                const u32 off = swz((u32)(nCh*8 + e)*64u + (u32)kRow*2u);
                *(u16*)(lds +  8192 + off) = (u16)vr[e];
                *(u16*)(lds + 12288 + off) = (u16)vi[e];
            }
        }
    }
    __syncthreads();

    // ---- main loop: 8 K-steps, stage t+1 while computing t ----
    for (int it = 0; it < 8; ++it) {
        const u32 cb = (u32)(it & 1) * 16384u;         // compute buffer
        const u32 sb = cb ^ 16384u;                    // stage buffer
        s16x8 nvr, nvi;
        if (it < 7) {
            const int k1 = 32*(it + 1);
            gll16(pA + k1,       lds, sb +     0u + wvoff);
            gll16(pA + PLQ + k1, lds, sb +  4096u + wvoff);
            if (TRB == 0) {
                gll16(pB + k1,       lds, sb +  8192u + wvoff);
                gll16(pB + PLQ + k1, lds, sb + 12288u + wvoff);
            } else {
                nvr = *(const s16x8*)(B +       (size_t)(k1 + kRow)*DD + bn + nCh*8);
                nvi = *(const s16x8*)(B + PLQ + (size_t)(k1 + kRow)*DD + bn + nCh*8);
            }
        }

        // ---- fragments from compute buffer ----
        s16x8 ar[2], ai[2], br[2], bi[2];
        #pragma unroll
        for (int fm = 0; fm < 2; ++fm) {
            const u32 so = swz((u32)(wrow + fm*16 + lc)*64u + (u32)lg*16u);
            ar[fm] = *(const s16x8*)(lds + cb + so);
            ai[fm] = *(const s16x8*)(lds + cb + 4096 + so);
        }
        #pragma unroll
        for (int fn = 0; fn < 2; ++fn) {
            const u32 so = swz((u32)(wcol + fn*16 + lc)*64u + (u32)lg*16u);
            br[fn] = *(const s16x8*)(lds + cb +  8192 + so);
            bi[fn] = *(const s16x8*)(lds + cb + 12288 + so);
        }
        // pass 1: imag acc
        #pragma unroll
        for (int fm = 0; fm < 2; ++fm)
            #pragma unroll
            for (int fn = 0; fn < 2; ++fn) {
                accI[fm][fn] = __builtin_amdgcn_mfma_f32_16x16x32_bf16(ar[fm], bi[fn], accI[fm][fn], 0, 0, 0);
                accI[fm][fn] = __builtin_amdgcn_mfma_f32_16x16x32_bf16(ai[fm], br[fn], accI[fm][fn], 0, 0, 0);
            }
        // flip ai, pass 2: real acc = ar@br + (-ai)@bi
        #pragma unroll
        for (int fm = 0; fm < 2; ++fm) ai[fm] ^= (short)0x8000u;
        #pragma unroll
        for (int fm = 0; fm < 2; ++fm)
            #pragma unroll
            for (int fn = 0; fn < 2; ++fn) {
                accR[fm][fn] = __builtin_amdgcn_mfma_f32_16x16x32_bf16(ar[fm], br[fn], accR[fm][fn], 0, 0, 0);
                accR[fm][fn] = __builtin_amdgcn_mfma_f32_16x16x32_bf16(ai[fm], bi[fn], accR[fm][fn], 0, 0, 0);
            }

        // TRB=1: write staged B regs into stage buffer (after MFMAs — T14 split)
        if (TRB == 1 && it < 7) {
            #pragma unroll
            for (int e = 0; e < 8; ++e) {
                const u32 off = swz((u32)(nCh*8 + e)*64u + (u32)kRow*2u);
                *(u16*)(lds + sb +  8192 + off) = (u16)nvr[e];
                *(u16*)(lds + sb + 12288 + off) = (u16)nvi[e];
            }
        }
        __syncthreads();
    }

    // ---- epilogue ----
    u16* oN = outN ? outN + (size_t)(z*cS + cO) * SLOTB : nullptr;
    u16* oT = outT ? outT + (size_t)(z*cS + cO) * SLOTB : nullptr;
    const u16* x1 = X1b ? X1b + (size_t)(z*x1S + x1O) * SLOTB : nullptr;
    const u16* x2 = X2b ? X2b + (size_t)(z*x2S + x2O) * SLOTB : nullptr;

    #pragma unroll
    for (int fm = 0; fm < 2; ++fm)
        #pragma unroll
        for (int fn = 0; fn < 2; ++fn) {
            const int rb = bm + wrow + fm*16 + lg*4;
            const int c  = bn + wcol + fn*16 + lc;
            u16 tR[4], tI[4];
            #pragma unroll
            for (int j = 0; j < 4; ++j) {
                const int r = rb + j;
                float x1r = 0.f, x1i = 0.f, x2r = 0.f, x2i = 0.f;
                if (x1) { x1r = bf2f(x1[(size_t)r*DD + c]);
                          x1i = bf2f(x1[PLQ + (size_t)r*DD + c]); }
                if (x2) { x2r = bf2f(x2[(size_t)r*DD + c]);
                          x2i = bf2f(x2[PLQ + (size_t)r*DD + c]); }
                if (oN) {
                    oN[(size_t)r*DD + c]       = f2bf(aN*accR[fm][fn][j] + bN1*x1r + bN2*x2r);
                    oN[PLQ + (size_t)r*DD + c] = f2bf(aN*accI[fm][fn][j] + bN1*x1i + bN2*x2i);
                }
                tR[j] = f2bf(aT*accR[fm][fn][j] + bT1*x1r + bT2*x2r);
                tI[j] = f2bf(aT*accI[fm][fn][j] + bT1*x1i + bT2*x2i);
            }
            if (oT) {
                *(ushort4*)(oT + (size_t)c*DD + rb)       = make_ushort4(tR[0], tR[1], tR[2], tR[3]);
                *(ushort4*)(oT + PLQ + (size_t)c*DD + rb) = make_ushort4(tI[0], tI[1], tI[2], tI[3]);
            }
        }
}

// ---------------------------------------------------------------------------
// final: v = s0 + Etot@s0 ; c = sum(v[diag]) ; sT = v/c ; fid = ||sT-tgt||_F
// ---------------------------------------------------------------------------
__global__ __launch_bounds__(256)
void final_kernel(const u16* __restrict__ Et,
                  const float* __restrict__ s0r, const float* __restrict__ s0i,
                  const float* __restrict__ tgr, const float* __restrict__ tgi,
                  float* __restrict__ out, int outSize)
{
    __shared__ float sr[DD], si[DD], vr[DD], vi[DD], red[DD];
    __shared__ float cR, cI;
    const int t = threadIdx.x;
    sr[t] = s0r[t];
    si[t] = s0i[t];
    __syncthreads();

    const u16* Er = Et + (size_t)t*DD;
    const u16* Ei = Et + PLQ + (size_t)t*DD;
    float ar = sr[t], ai = si[t];
    for (int kk = 0; kk < DD/8; ++kk) {
        const s16x8 er = *(const s16x8*)(Er + kk*8);
        const s16x8 ei = *(const s16x8*)(Ei + kk*8);
        #pragma unroll
        for (int j = 0; j < 8; ++j) {
            const float pr = bf2f((u16)er[j]);
            const float pi = bf2f((u16)ei[j]);
            const int k = kk*8 + j;
            ar += pr*sr[k] - pi*si[k];
            ai += pr*si[k] + pi*sr[k];
        }
    }
    vr[t] = ar; vi[t] = ai;
    __syncthreads();

    if (t == 0) {
        float xr = 0.f, xi = 0.f;
        for (int i = 0; i < 16; ++i) { xr += vr[i*17]; xi += vi[i*17]; }
        cR = xr; cI = xi;
    }
    __syncthreads();

    const float den = cR*cR + cI*cI;
    const float str = (ar*cR + ai*cI) / den;
    const float sti = (ai*cR - ar*cI) / den;

    const float dr = str - tgr[t];
    const float di = sti - tgi[t];
    red[t] = dr*dr + di*di;
    __syncthreads();
    for (int s = 128; s > 0; s >>= 1) {
        if (t < s) red[t] += red[t + s];
        __syncthreads();
    }
    const float fid = sqrtf(red[0]);

    if (outSize >= 2*DD + 1) {
        out[2*t] = str; out[2*t+1] = sti;
        if (t == 0) out[2*DD] = fid;
    } else if (outSize == 2*DD) {
        out[2*t] = str; out[2*t+1] = sti;
    } else {
        out[t] = str;
        if (t == 0 && outSize > DD) out[DD] = fid;
    }
}

// ---------------------------------------------------------------------------
extern "C" void kernel_launch(void* const* d_in, const int* in_sizes, int n_in,
                              void* d_out, int out_size, void* d_ws, size_t ws_size,
                              hipStream_t stream)
{
    (void)in_sizes; (void)n_in;
    const float* cr   = (const float*)d_in[0];
    const float* ci   = (const float*)d_in[1];
    const float* dre  = (const float*)d_in[2];
    const float* dimg = (const float*)d_in[3];
    const float* gre  = (const float*)d_in[4];
    const float* gim  = (const float*)d_in[5];
    const float* s0r  = (const float*)d_in[6];
    const float* s0i  = (const float*)d_in[7];
    const float* tgr  = (const float*)d_in[8];
    const float* tgi  = (const float*)d_in[9];

    // Degree-4 Paterson-Stockmeyer: E = c1X + c2P2 + P2@(c3X + c4P2),
    // P2 = X@X. ||X|| ~ 0.1-0.3 -> truncation ||X||^5/120 << bf16 noise.
    const float c1 = 1.f, c2 = 0.5f, c3 = 1.f/6.f, c4 = 1.f/24.f;

    u16* ws = (u16*)d_ws;
    u16* P  = ws;                          // 128 N-slots: expm deviations E_ts
    u16* CB = ws + 128L * SLOTB;           // chunk region: 4C slots (also tree ping)

    long availU = (long)(ws_size / 2) - 128L * SLOTB;
    int C = availU > 0 ? (int)(availU / (4L * SLOTB)) : 16;
    if (C > NTS) C = NTS;
    if (C < 16)  C = 16;                   // tree ping (64 slots) must fit in 4C

    for (int ts0 = 0; ts0 < NTS; ts0 += C) {
        int nb = NTS - ts0; if (nb > C) nb = C;
        u16* Xn = CB;
        u16* Xt = CB + 1L*C*SLOTB;
        u16* P2 = CB + 2L*C*SLOTB;
        u16* LT = CB + 3L*C*SLOTB;

        build_kernel<<<dim3(16, nb), 256, 0, stream>>>(
            cr, ci, dre, dimg, gre, gim, Xn, Xt, ts0);

        const dim3 grid(4, 4, nb);
        // G1: acc = X@X ; P2 = acc (N) ; LT = c4*acc + c3*X (T)
        cgemm<0><<<grid, 256, 0, stream>>>(Xn, Xt, P2, LT, Xn, nullptr,
            1.f, 0.f, 0.f,  c4, c3, 0.f,
            1,0, 1,0, 1,0, 1,0, 0,0);
        // G2: acc = P2@L ; E = acc + c1*X + c2*P2 -> P[ts0+z] (N)
        cgemm<0><<<grid, 256, 0, stream>>>(P2, LT, P, nullptr, Xn, P2,
            1.f, c1, c2,  0.f, 0.f, 0.f,
            1,0, 1,0, 1,ts0, 1,0, 1,0);
    }

    // ---- product tree (ping-pong, race-free): E' = Ea@Eb + Ea + Eb ----
    u16* TA  = CB;                         // 64 slots (chunk buffers dead now)
    u16* src = P;
    u16* dst = TA;
    int n = NTS;
    while (n > 1) {
        cgemm<1><<<dim3(4, 4, n/2), 256, 0, stream>>>(
            src, src, dst, nullptr, src, src,
            1.f, 1.f, 1.f,  0.f, 0.f, 0.f,
            2,1, 2,0, 1,0, 2,1, 2,0);
        u16* ns = dst;
        dst = (dst == TA) ? P : TA;
        src = ns;
        n >>= 1;
    }

    final_kernel<<<1, 256, 0, stream>>>(src, s0r, s0i, tgr, tgi,
                                        (float*)d_out, out_size);
}

// Round 6
// 256.391 us; speedup vs baseline: 1.9097x; 1.0357x over previous
//
#include <hip/hip_runtime.h>
#include <math.h>

#define DD    256
#define PLQ   65536           // plane elems (u16) = 256*256
#define SLOTB 131072          // complex slot elems (u16): re plane + im plane
#define NTS   128
#define DT_C  0.02f

typedef unsigned short u16;
typedef unsigned int   u32;
typedef __attribute__((ext_vector_type(8))) short s16x8;
typedef __attribute__((ext_vector_type(4))) float f32x4;

typedef __attribute__((address_space(1))) const unsigned int GU32;
typedef __attribute__((address_space(3))) unsigned int LU32;

__device__ __forceinline__ u32 swz(u32 off) {       // 16B-chunk XOR swizzle (involution)
    return off ^ (((off >> 7) & 3u) << 4);
}
__device__ __forceinline__ u16 f2bf(float f) {
    u32 u = __float_as_uint(f);
    return (u16)((u + 0x7FFFu + ((u >> 16) & 1u)) >> 16);
}
__device__ __forceinline__ float bf2f(u16 h) {
    return __uint_as_float(((u32)h) << 16);
}
__device__ __forceinline__ void gll16(const u16* g, char* ldsBase, u32 ldsByteOff) {
    u32 off = (u32)__builtin_amdgcn_readfirstlane((int)ldsByteOff);
    __builtin_amdgcn_global_load_lds((GU32*)g, (LU32*)(ldsBase + off), 16, 0, 0);
}

// ---------------------------------------------------------------------------
// build: X = DT * A_ts (bf16, N-layout only).
// ---------------------------------------------------------------------------
__global__ __launch_bounds__(256)
void build_kernel(const float* __restrict__ cr, const float* __restrict__ ci,
                  const float* __restrict__ dre, const float* __restrict__ dimg,
                  const float* __restrict__ gre, const float* __restrict__ gim,
                  u16* __restrict__ Xn, int ts0)
{
    const int ts = blockIdx.y;
    const int k  = ts0 + ts;
    const int bx = blockIdx.x;                 // 0..15
    const int r0 = (bx >> 2) * 64, c0 = (bx & 3) * 64;
    const int t  = threadIdx.x;
    const int tr = t >> 4;                     // 0..15
    const int tc = (t & 15) * 4;               // 0..60

    const float c0f = cr[2*k], c1f = cr[2*k+1];
    const float e0f = ci[2*k], e1f = ci[2*k+1];

    u16* XN = Xn + (size_t)ts * SLOTB;

    #pragma unroll
    for (int g = 0; g < 4; ++g) {
        const int lr  = g*16 + tr;
        const int idx = (r0 + lr)*DD + (c0 + tc);
        const float4 g0r = *(const float4*)&gre[0*PLQ + idx];
        const float4 g1r = *(const float4*)&gre[1*PLQ + idx];
        const float4 g2r = *(const float4*)&gre[2*PLQ + idx];
        const float4 g3r = *(const float4*)&gre[3*PLQ + idx];
        const float4 g0i = *(const float4*)&gim[0*PLQ + idx];
        const float4 g1i = *(const float4*)&gim[1*PLQ + idx];
        const float4 g2i = *(const float4*)&gim[2*PLQ + idx];
        const float4 g3i = *(const float4*)&gim[3*PLQ + idx];
        const float4 d_r = *(const float4*)&dre[idx];
        const float4 d_i = *(const float4*)&dimg[idx];
        const float* gr00 = &g0r.x; const float* gr01 = &g1r.x;
        const float* gr10 = &g2r.x; const float* gr11 = &g3r.x;
        const float* gi00 = &g0i.x; const float* gi01 = &g1i.x;
        const float* gi10 = &g2i.x; const float* gi11 = &g3i.x;
        const float* dr4  = &d_r.x; const float* di4  = &d_i.x;
        ushort4 hr, hi;
        u16* hrp = &hr.x; u16* hip = &hi.x;
        #pragma unroll
        for (int j = 0; j < 4; ++j) {
            const float are = dr4[j] + c0f*(gr00[j]+gr01[j]) + c1f*(gr10[j]+gr11[j])
                                     - e0f*(gi00[j]-gi01[j]) - e1f*(gi10[j]-gi11[j]);
            const float aim = di4[j] + c0f*(gi00[j]+gi01[j]) + c1f*(gi10[j]+gi11[j])
                                     + e0f*(gr00[j]-gr01[j]) + e1f*(gr10[j]-gr11[j]);
            hrp[j] = f2bf(DT_C * are);
            hip[j] = f2bf(DT_C * aim);
        }
        *(ushort4*)&XN[idx]       = hr;
        *(ushort4*)&XN[PLQ + idx] = hi;
    }
}

// ---------------------------------------------------------------------------
// Batched complex bf16 MFMA GEMM, 64x64 tile, 4 waves, BK=32, double-buffered
// 2-phase pipeline.  A: N-layout via gll16.  B: TRB=0 -> T-layout via gll16;
// TRB=1 -> N-layout, reg-load early + LDS scatter after MFMAs.
//   N-write: aN*acc + bN1*X1 + bN2*X2 ; T-write: aT*acc + bT1*X1 + bT2*X2.
// ---------------------------------------------------------------------------
template<int TRB>
__global__ __launch_bounds__(256)
void cgemm(const u16* __restrict__ Ab, const u16* __restrict__ Bb,
           u16* __restrict__ outN, u16* __restrict__ outT,
           const u16* __restrict__ X1b, const u16* __restrict__ X2b,
           float aN, float bN1, float bN2,
           float aT, float bT1, float bT2,
           int aS, int aO, int bS, int bO, int cS, int cO,
           int x1S, int x1O, int x2S, int x2O)
{
    __shared__ char lds[32768];   // 2 x { Are[64][32] | Aim | Bre[64][32](n-major) | Bim }

    // ---- bijective XCD-chunked block swizzle (nwg = 16*nz, always %8==0) ----
    const u32 nwg = 16u * (u32)gridDim.z;
    const u32 wg  = (u32)blockIdx.x + 4u*(u32)blockIdx.y + 16u*(u32)blockIdx.z;
    const u32 q   = nwg >> 3;
    const u32 w   = (wg & 7u) * q + (wg >> 3);
    const int bn = (int)(w & 3u) * 64;
    const int bm = (int)((w >> 2) & 3u) * 64;
    const int z  = (int)(w >> 4);

    const u16* __restrict__ A = Ab + (size_t)(z*aS + aO) * SLOTB;
    const u16* __restrict__ B = Bb + (size_t)(z*bS + bO) * SLOTB;

    const int t = threadIdx.x;

    // gll16 staging mapping: dest chunk D=t*16 -> logical L=swz(D)
    const u32 D0 = (u32)t * 16u;
    const u32 L0 = swz(D0);
    const int sr = (int)(L0 >> 6);             // tile row 0..63
    const int sk = (int)((L0 & 63u) >> 1);     // k elem offset (16B aligned)
    const u32 wvoff = ((u32)(t >> 6)) * 1024u;

    const u16* pA = A + (size_t)(bm + sr)*DD + sk;
    const u16* pB = (TRB == 0) ? (B + (size_t)(bn + sr)*DD + sk) : nullptr;

    // TRB=1 staging mapping (B from N-layout [k][n])
    const int kRow = t >> 3;                   // 0..31
    const int nCh  = t & 7;                    // 0..7 -> n0 = nCh*8

    const int wv = t >> 6, ln = t & 63;
    const int wrow = (wv >> 1) * 32, wcol = (wv & 1) * 32;
    const int lg = ln >> 4, lc = ln & 15;

    f32x4 accR[2][2], accI[2][2];
    #pragma unroll
    for (int i = 0; i < 2; ++i)
        #pragma unroll
        for (int j = 0; j < 2; ++j) {
            accR[i][j] = (f32x4){0.f,0.f,0.f,0.f};
            accI[i][j] = (f32x4){0.f,0.f,0.f,0.f};
        }

    // ---- prologue: stage K-tile 0 into buffer 0 ----
    {
        gll16(pA,       lds,     0u + wvoff);
        gll16(pA + PLQ, lds,  4096u + wvoff);
        if (TRB == 0) {
            gll16(pB,       lds,  8192u + wvoff);
            gll16(pB + PLQ, lds, 12288u + wvoff);
        } else {
            const s16x8 vr = *(const s16x8*)(B +       (size_t)kRow*DD + bn + nCh*8);
            const s16x8 vi = *(const s16x8*)(B + PLQ + (size_t)kRow*DD + bn + nCh*8);
            #pragma unroll
            for (int e = 0; e < 8; ++e) {
                const u32 off = swz((u32)(nCh*8 + e)*64u + (u32)kRow*2u);
                *(u16*)(lds +  8192 + off) = (u16)vr[e];
                *(u16*)(lds + 12288 + off) = (u16)vi[e];
            }
        }
    }
    __syncthreads();

    // ---- main loop: 8 K-steps, stage t+1 while computing t ----
    for (int it = 0; it < 8; ++it) {
        const u32 cb = (u32)(it & 1) * 16384u;         // compute buffer
        const u32 sb = cb ^ 16384u;                    // stage buffer
        s16x8 nvr, nvi;
        if (it < 7) {
            const int k1 = 32*(it + 1);
            gll16(pA + k1,       lds, sb +     0u + wvoff);
            gll16(pA + PLQ + k1, lds, sb +  4096u + wvoff);
            if (TRB == 0) {
                gll16(pB + k1,       lds, sb +  8192u + wvoff);
                gll16(pB + PLQ + k1, lds, sb + 12288u + wvoff);
            } else {
                nvr = *(const s16x8*)(B +       (size_t)(k1 + kRow)*DD + bn + nCh*8);
                nvi = *(const s16x8*)(B + PLQ + (size_t)(k1 + kRow)*DD + bn + nCh*8);
            }
        }

        // ---- fragments from compute buffer ----
        s16x8 ar[2], ai[2], br[2], bi[2];
        #pragma unroll
        for (int fm = 0; fm < 2; ++fm) {
            const u32 so = swz((u32)(wrow + fm*16 + lc)*64u + (u32)lg*16u);
            ar[fm] = *(const s16x8*)(lds + cb + so);
            ai[fm] = *(const s16x8*)(lds + cb + 4096 + so);
        }
        #pragma unroll
        for (int fn = 0; fn < 2; ++fn) {
            const u32 so = swz((u32)(wcol + fn*16 + lc)*64u + (u32)lg*16u);
            br[fn] = *(const s16x8*)(lds + cb +  8192 + so);
            bi[fn] = *(const s16x8*)(lds + cb + 12288 + so);
        }
        // pass 1: imag acc
        #pragma unroll
        for (int fm = 0; fm < 2; ++fm)
            #pragma unroll
            for (int fn = 0; fn < 2; ++fn) {
                accI[fm][fn] = __builtin_amdgcn_mfma_f32_16x16x32_bf16(ar[fm], bi[fn], accI[fm][fn], 0, 0, 0);
                accI[fm][fn] = __builtin_amdgcn_mfma_f32_16x16x32_bf16(ai[fm], br[fn], accI[fm][fn], 0, 0, 0);
            }
        // flip ai, pass 2: real acc = ar@br + (-ai)@bi
        #pragma unroll
        for (int fm = 0; fm < 2; ++fm) ai[fm] ^= (short)0x8000u;
        #pragma unroll
        for (int fm = 0; fm < 2; ++fm)
            #pragma unroll
            for (int fn = 0; fn < 2; ++fn) {
                accR[fm][fn] = __builtin_amdgcn_mfma_f32_16x16x32_bf16(ar[fm], br[fn], accR[fm][fn], 0, 0, 0);
                accR[fm][fn] = __builtin_amdgcn_mfma_f32_16x16x32_bf16(ai[fm], bi[fn], accR[fm][fn], 0, 0, 0);
            }

        // TRB=1: write staged B regs into stage buffer (after MFMAs)
        if (TRB == 1 && it < 7) {
            #pragma unroll
            for (int e = 0; e < 8; ++e) {
                const u32 off = swz((u32)(nCh*8 + e)*64u + (u32)kRow*2u);
                *(u16*)(lds + sb +  8192 + off) = (u16)nvr[e];
                *(u16*)(lds + sb + 12288 + off) = (u16)nvi[e];
            }
        }
        __syncthreads();
    }

    // ---- epilogue ----
    u16* oN = outN ? outN + (size_t)(z*cS + cO) * SLOTB : nullptr;
    u16* oT = outT ? outT + (size_t)(z*cS + cO) * SLOTB : nullptr;
    const u16* x1 = X1b ? X1b + (size_t)(z*x1S + x1O) * SLOTB : nullptr;
    const u16* x2 = X2b ? X2b + (size_t)(z*x2S + x2O) * SLOTB : nullptr;

    #pragma unroll
    for (int fm = 0; fm < 2; ++fm)
        #pragma unroll
        for (int fn = 0; fn < 2; ++fn) {
            const int rb = bm + wrow + fm*16 + lg*4;
            const int c  = bn + wcol + fn*16 + lc;
            u16 tR[4], tI[4];
            #pragma unroll
            for (int j = 0; j < 4; ++j) {
                const int r = rb + j;
                float x1r = 0.f, x1i = 0.f, x2r = 0.f, x2i = 0.f;
                if (x1) { x1r = bf2f(x1[(size_t)r*DD + c]);
                          x1i = bf2f(x1[PLQ + (size_t)r*DD + c]); }
                if (x2) { x2r = bf2f(x2[(size_t)r*DD + c]);
                          x2i = bf2f(x2[PLQ + (size_t)r*DD + c]); }
                if (oN) {
                    oN[(size_t)r*DD + c]       = f2bf(aN*accR[fm][fn][j] + bN1*x1r + bN2*x2r);
                    oN[PLQ + (size_t)r*DD + c] = f2bf(aN*accI[fm][fn][j] + bN1*x1i + bN2*x2i);
                }
                tR[j] = f2bf(aT*accR[fm][fn][j] + bT1*x1r + bT2*x2r);
                tI[j] = f2bf(aT*accI[fm][fn][j] + bT1*x1i + bT2*x2i);
            }
            if (oT) {
                *(ushort4*)(oT + (size_t)c*DD + rb)       = make_ushort4(tR[0], tR[1], tR[2], tR[3]);
                *(ushort4*)(oT + PLQ + (size_t)c*DD + rb) = make_ushort4(tI[0], tI[1], tI[2], tI[3]);
            }
        }
}

// ---------------------------------------------------------------------------
// final: v = s0 + Etot@s0 ; c = sum(v[diag]) ; sT = v/c ; fid = ||sT-tgt||_F
// ---------------------------------------------------------------------------
__global__ __launch_bounds__(256)
void final_kernel(const u16* __restrict__ Et,
                  const float* __restrict__ s0r, const float* __restrict__ s0i,
                  const float* __restrict__ tgr, const float* __restrict__ tgi,
                  float* __restrict__ out, int outSize)
{
    __shared__ float sr[DD], si[DD], vr[DD], vi[DD], red[DD];
    __shared__ float cR, cI;
    const int t = threadIdx.x;
    sr[t] = s0r[t];
    si[t] = s0i[t];
    __syncthreads();

    const u16* Er = Et + (size_t)t*DD;
    const u16* Ei = Et + PLQ + (size_t)t*DD;
    float ar = sr[t], ai = si[t];
    for (int kk = 0; kk < DD/8; ++kk) {
        const s16x8 er = *(const s16x8*)(Er + kk*8);
        const s16x8 ei = *(const s16x8*)(Ei + kk*8);
        #pragma unroll
        for (int j = 0; j < 8; ++j) {
            const float pr = bf2f((u16)er[j]);
            const float pi = bf2f((u16)ei[j]);
            const int k = kk*8 + j;
            ar += pr*sr[k] - pi*si[k];
            ai += pr*si[k] + pi*sr[k];
        }
    }
    vr[t] = ar; vi[t] = ai;
    __syncthreads();

    if (t == 0) {
        float xr = 0.f, xi = 0.f;
        for (int i = 0; i < 16; ++i) { xr += vr[i*17]; xi += vi[i*17]; }
        cR = xr; cI = xi;
    }
    __syncthreads();

    const float den = cR*cR + cI*cI;
    const float str = (ar*cR + ai*cI) / den;
    const float sti = (ai*cR - ar*cI) / den;

    const float dr = str - tgr[t];
    const float di = sti - tgi[t];
    red[t] = dr*dr + di*di;
    __syncthreads();
    for (int s = 128; s > 0; s >>= 1) {
        if (t < s) red[t] += red[t + s];
        __syncthreads();
    }
    const float fid = sqrtf(red[0]);

    if (outSize >= 2*DD + 1) {
        out[2*t] = str; out[2*t+1] = sti;
        if (t == 0) out[2*DD] = fid;
    } else if (outSize == 2*DD) {
        out[2*t] = str; out[2*t+1] = sti;
    } else {
        out[t] = str;
        if (t == 0 && outSize > DD) out[DD] = fid;
    }
}

// ---------------------------------------------------------------------------
extern "C" void kernel_launch(void* const* d_in, const int* in_sizes, int n_in,
                              void* d_out, int out_size, void* d_ws, size_t ws_size,
                              hipStream_t stream)
{
    (void)in_sizes; (void)n_in;
    const float* cr   = (const float*)d_in[0];
    const float* ci   = (const float*)d_in[1];
    const float* dre  = (const float*)d_in[2];
    const float* dimg = (const float*)d_in[3];
    const float* gre  = (const float*)d_in[4];
    const float* gim  = (const float*)d_in[5];
    const float* s0r  = (const float*)d_in[6];
    const float* s0i  = (const float*)d_in[7];
    const float* tgr  = (const float*)d_in[8];
    const float* tgi  = (const float*)d_in[9];

    // Degree-4 Paterson-Stockmeyer: E = c1X + c2P2 + P2@(c3X + c4P2), P2=X@X.
    const float c1 = 1.f, c2 = 0.5f, c3 = 1.f/6.f, c4 = 1.f/24.f;

    u16* ws = (u16*)d_ws;
    const long slots = (long)(ws_size / 2) / SLOTB;

    if (slots >= 384) {
        // ================= FAST PATH: single chunk z=128, 3 regions ==========
        u16* RX = ws;                      // X, then E (in-place G2 output)
        u16* R1 = ws + 128L * SLOTB;       // P2, then tree ping
        u16* R2 = ws + 256L * SLOTB;       // LT, then tree pong

        build_kernel<<<dim3(16, 128), 256, 0, stream>>>(
            cr, ci, dre, dimg, gre, gim, RX, 0);

        const dim3 g128(4, 4, 128);
        // G1: acc = X@X ; P2=acc (N->R1) ; LT = c4*acc + c3*X (T->R2)
        cgemm<1><<<g128, 256, 0, stream>>>(RX, RX, R1, R2, RX, nullptr,
            1.f, 0.f, 0.f,  c4, c3, 0.f,
            1,0, 1,0, 1,0, 1,0, 0,0);
        // G2: acc = P2@LT ; E = acc + c1*X + c2*P2 -> RX (in-place, N)
        cgemm<0><<<g128, 256, 0, stream>>>(R1, R2, RX, nullptr, RX, R1,
            1.f, c1, c2,  0.f, 0.f, 0.f,
            1,0, 1,0, 1,0, 1,0, 1,0);

        // ---- tree: E' = Ea@Eb + Ea + Eb.  L1: scatter-B, dual N+T out ----
        cgemm<1><<<dim3(4, 4, 64), 256, 0, stream>>>(
            RX, RX, R1, R1 + 64L*SLOTB, RX, RX,
            1.f, 1.f, 1.f,  1.f, 1.f, 1.f,
            2,1, 2,0, 1,0, 2,1, 2,0);
        // L2..L7: fast gll16 both sides; src has N[0..n) + T[n..2n)
        u16* cur = R1;
        u16* oth = R2;
        for (int n = 64; n > 1; n >>= 1) {
            const bool last = (n == 2);
            cgemm<0><<<dim3(4, 4, n/2), 256, 0, stream>>>(
                cur, cur, oth, last ? nullptr : oth + (size_t)(n/2)*SLOTB,
                cur, cur,
                1.f, 1.f, 1.f,  1.f, 1.f, 1.f,
                2,1, 2,(int)n, 1,0, 2,1, 2,0);
            u16* tmp = cur; cur = oth; oth = tmp;
        }
        final_kernel<<<1, 256, 0, stream>>>(cur, s0r, s0i, tgr, tgi,
                                            (float*)d_out, out_size);
    } else {
        // ================= FALLBACK: chunked (P + 3C regions) ================
        u16* P  = ws;
        u16* CB = ws + 128L * SLOTB;
        int C = (int)((slots - 128) / 3);
        if (C > NTS) C = NTS;
        if (C < 22)  C = 22;               // tree ping (64 slots) needs 3C>=64

        for (int ts0 = 0; ts0 < NTS; ts0 += C) {
            int nb = NTS - ts0; if (nb > C) nb = C;
            u16* Xn = CB;
            u16* P2 = CB + 1L*C*SLOTB;
            u16* LT = CB + 2L*C*SLOTB;

            build_kernel<<<dim3(16, nb), 256, 0, stream>>>(
                cr, ci, dre, dimg, gre, gim, Xn, ts0);

            const dim3 grid(4, 4, nb);
            cgemm<1><<<grid, 256, 0, stream>>>(Xn, Xn, P2, LT, Xn, nullptr,
                1.f, 0.f, 0.f,  c4, c3, 0.f,
                1,0, 1,0, 1,0, 1,0, 0,0);
            cgemm<0><<<grid, 256, 0, stream>>>(P2, LT, P, nullptr, Xn, P2,
                1.f, c1, c2,  0.f, 0.f, 0.f,
                1,0, 1,0, 1,ts0, 1,0, 1,0);
        }

        u16* TA  = CB;
        u16* src = P;
        u16* dst = TA;
        int n = NTS;
        while (n > 1) {
            cgemm<1><<<dim3(4, 4, n/2), 256, 0, stream>>>(
                src, src, dst, nullptr, src, src,
                1.f, 1.f, 1.f,  0.f, 0.f, 0.f,
                2,1, 2,0, 1,0, 2,1, 2,0);
            u16* ns = dst;
            dst = (dst == TA) ? P : TA;
            src = ns;
            n >>= 1;
        }
        final_kernel<<<1, 256, 0, stream>>>(src, s0r, s0i, tgr, tgi,
                                            (float*)d_out, out_size);
    }
}